// Round 2
// baseline (15156.192 us; speedup 1.0000x reference)
//
#include <hip/hip_runtime.h>

// SCLSTM on MI355X — R6: 2-barrier step schedule, single-counter L2 group barrier,
// wave0-only cell update, overlap staging with barrier tail.
//
// Dead code (verified R1-R3): s==0 forever => st==0, slot_info==tanh(sb[l]).
// Remaining: 2-layer LSTM B=64,T=512,H=512; layers pipelined on disjoint block sets.
//
// R5 post-mortem: still sync-latency-bound (MfmaUtil 6.3, VALU 10.5, HBM 1.3%);
// per-step 3.42us vs ~1us dependency chain. Cost = 4 __syncthreads + 2-phase flag
// barrier + serial staging after S5 + A's MALL store acks inside vmcnt drain.
// R6: (1) cell update in wave0 only (4 cells/lane) -> no S4: wave0 ring-stores,
// vmcnt(0), then ONE workgroup-scope L2 atomic add (agent fallback if multi-XCD).
// (2) all waves poll the counter (sc0, one line) and stage immediately -> no S5.
// (3) waves1-7 stage non-recurrent K-half for t+1 right after S2 (overlaps wave0
// tail + B's prog_up wait). (4) A->B ring0 stores issue AFTER the counter add;
// prog_up publish lagged 1 step (covered by next step's vmcnt; D0=8 slack).

typedef unsigned short ushort;
typedef unsigned long long u64;
using bfrag = __attribute__((ext_vector_type(8))) short;
using cfrag = __attribute__((ext_vector_type(4))) float;
using i4    = __attribute__((ext_vector_type(4))) int;

constexpr int NBLK = 256, NTHR = 512;
constexpr int Bsz = 64, Tt = 512, Hsz = 512;
constexpr int D0 = 8;                     // ring0 (A->B) depth
constexpr int DP = 2;                     // private recurrence ring depth

constexpr long long OUT_HT = (long long)Bsz * Tt * Hsz;
constexpr long long OUT_CT = OUT_HT + (long long)Bsz * 2 * Hsz;
constexpr long long OUT_ST = OUT_CT + (long long)Bsz * 2 * Hsz;

// ws layout (bytes)
constexpr int WS_PROG_A = 16 * 1024;
constexpr int WS_PROG_B = 17 * 1024;
constexpr int WS_CNT    = 18 * 1024;                          // 8 counters, 256B apart
constexpr int WS_XCC    = 20 * 1024;                          // 2 x 4 x 32 x 16 ints
constexpr int WS_RING0  = 64 * 1024;                          // D0 x 64 x 512 ushort
constexpr int WS_RING1  = WS_RING0 + D0 * Bsz * Hsz * 2;      // DP x ... (B private)
constexpr int WS_RINGA  = WS_RING1 + DP * Bsz * Hsz * 2;      // DP x ... (A private)
constexpr int WS_TOTAL  = WS_RINGA + DP * Bsz * Hsz * 2;

__global__ __launch_bounds__(256) void sclstm_init(float* __restrict__ ws,
                                                   float* __restrict__ out) {
    int i = blockIdx.x * blockDim.x + threadIdx.x, st = gridDim.x * blockDim.x;
    for (int k = i; k < WS_TOTAL / 4; k += st) ws[k] = 0.f;
    for (int k = i; k < Bsz * 128; k += st) out[OUT_ST + k] = 0.f;  // st == 0 always
}

__device__ __forceinline__ float sigm(float x) { return 1.f / (1.f + __expf(-x)); }
__device__ __forceinline__ float ftanh(float x) {
    float e = __expf(2.f * x);
    return 1.f - 2.f / (e + 1.f);
}
__device__ __forceinline__ ushort f2bf(float f) {
    unsigned u = __builtin_bit_cast(unsigned, f);
    u += 0x7FFFu + ((u >> 16) & 1u);
    return (ushort)(u >> 16);
}
__device__ __forceinline__ int aload(const int* p) {
    return __hip_atomic_load(p, __ATOMIC_RELAXED, __HIP_MEMORY_SCOPE_AGENT);
}
__device__ __forceinline__ int load_sc0(const int* p) {   // bypass L1, read own-XCD L2
    int v;
    asm volatile("global_load_dword %0, %1, off sc0\n\ts_waitcnt vmcnt(0)"
                 : "=v"(v) : "v"(p) : "memory");
    return v;
}
__device__ __forceinline__ void spin_agent(const int* p, int v) {
    int it = 0;
    while (aload(p) < v) {
        __builtin_amdgcn_s_sleep(1);
        if (((++it) & 1023) == 0)
            __builtin_amdgcn_fence(__ATOMIC_ACQUIRE, "agent");  // safety net only
    }
}
__device__ __forceinline__ void spin_cnt(const int* p, int v, int fast) {
    if (fast) {
        int it = 0;
        while (load_sc0(p) < v) {
            __builtin_amdgcn_s_sleep(1);
            if (((++it) & 255) == 0)
                __builtin_amdgcn_fence(__ATOMIC_ACQUIRE, "agent");  // safety net only
        }
    } else {
        spin_agent(p, v);
    }
}
__device__ __forceinline__ void cnt_add(int* p, int fast) {
    if (fast) (void)__hip_atomic_fetch_add(p, 1, __ATOMIC_RELAXED, __HIP_MEMORY_SCOPE_WORKGROUP);
    else      (void)__hip_atomic_fetch_add(p, 1, __ATOMIC_RELAXED, __HIP_MEMORY_SCOPE_AGENT);
}
__device__ __forceinline__ bfrag pack2(u64 q0, u64 q1) {
    bfrag v;
    v[0]=(short)(ushort)(q0); v[1]=(short)(ushort)(q0 >> 16);
    v[2]=(short)(ushort)(q0 >> 32); v[3]=(short)(ushort)(q0 >> 48);
    v[4]=(short)(ushort)(q1); v[5]=(short)(ushort)(q1 >> 16);
    v[6]=(short)(ushort)(q1 >> 32); v[7]=(short)(ushort)(q1 >> 48);
    return v;
}

__global__ __launch_bounds__(NTHR, 2) void sclstm_main(
    const float* __restrict__ inputs,   // (B,T,512) fp32
    const float* __restrict__ gW,       // (2, 2048, 1024) fp32
    const float* __restrict__ gb,       // (2, 2048)
    const float* __restrict__ sbias,    // (2, 512)
    float* __restrict__ out,
    float* __restrict__ ws)
{
    __shared__ __attribute__((aligned(16))) ushort frag_lds[32 * 512]; // 32 ks x 1KB
    __shared__ float part_lds[64 * 17 * 2];   // [(lrow*17+col)*2 + g]
    __shared__ int fast_sh;

    char* wsb = (char*)ws;
    const int tid = threadIdx.x, blk = blockIdx.x;
    const int setB = blk & 1;                  // 0: layer0 (producer), 1: layer1
    const int grp = (blk >> 1) & 3;            // batch tile
    const int myidx = blk >> 3;                // 0..31 feature tile within group
    const int L = setB;
    const int b0 = grp * 16, m0 = myidx * 16;

    int* prog_self = (int*)(wsb + (setB ? WS_PROG_B : WS_PROG_A)) + grp * 16;
    int* prog_up   = (int*)(wsb + WS_PROG_A) + grp * 16;   // B waits: h0 ready
    int* prog_down = (int*)(wsb + WS_PROG_B) + grp * 16;   // A ring0 backpressure
    int* cnt       = (int*)(wsb + WS_CNT) + (setB * 4 + grp) * 64;
    ushort* ring0 = (ushort*)(wsb + WS_RING0);
    ushort* ring1 = (ushort*)(wsb + WS_RING1);
    ushort* ringA = (ushort*)(wsb + WS_RINGA);
    ushort* ring_own = setB ? ring1 : ringA;   // private recurrence ring (L2-local)

    const int lane = tid & 63, wave = tid >> 6;
    const int tau = wave & 3, g = wave >> 2;   // gate tile, K-half (512 each)
    const int q = lane >> 4, lm = lane & 15;   // quad / batch-col-in-tile

    // ---- one-time: weights -> A-fragments (16 ksteps) = 64 VGPRs ----
    bfrag wv[16];
    {
        const int grow = tau * 512 + m0 + lm;
        const float* wrow = gW + ((size_t)L * 2048 + grow) * 1024 + g * 512 + q * 8;
        #pragma unroll
        for (int j = 0; j < 16; ++j) {
            const float* src = wrow + j * 32;
            float4 a = *(const float4*)src, b = *(const float4*)(src + 4);
            bfrag v;
            v[0]=(short)f2bf(a.x); v[1]=(short)f2bf(a.y); v[2]=(short)f2bf(a.z); v[3]=(short)f2bf(a.w);
            v[4]=(short)f2bf(b.x); v[5]=(short)f2bf(b.y); v[6]=(short)f2bf(b.z); v[7]=(short)f2bf(b.w);
            wv[j] = v;
        }
    }
    // ---- wave0 cell constants: 4 cells/lane (mi = q*4+k, batch col = lm) ----
    float biasw[4][4], slotw[4], cc[4];
    #pragma unroll
    for (int k = 0; k < 4; ++k) {
        #pragma unroll
        for (int tg = 0; tg < 4; ++tg)
            biasw[tg][k] = gb[L * 2048 + tg * 512 + m0 + q * 4 + k];
        slotw[k] = ftanh(sbias[L * 512 + m0 + q * 4 + k]);
        cc[k] = 0.f;
    }

    // ---- runtime check: is this sync group on one XCD? (agent fallback if not) ----
    int fast;
    {
        unsigned xcc = (unsigned)__builtin_amdgcn_s_getreg((31 << 11) | 20) & 0xFu; // HW_REG_XCC_ID
        int* xarr = (int*)(wsb + WS_XCC) + (setB * 4 + grp) * 32 * 16;
        if (tid == 0) {
            __hip_atomic_store(xarr + myidx * 16, (int)xcc + 1,
                               __ATOMIC_RELAXED, __HIP_MEMORY_SCOPE_AGENT);
            int ok = 1, ref = 0;
            for (int i = 0; i < 32; ++i) {
                int v;
                while ((v = aload(xarr + i * 16)) == 0) __builtin_amdgcn_s_sleep(2);
                if (i == 0) ref = v; else ok &= (v == ref);
            }
            fast_sh = ok;
        }
        __syncthreads();
        fast = fast_sh;
    }

    // stage one non-recurrent row (ks = r in 0..15): A: x(tt); B: h0(tt) from ring0
    auto stage_row = [&](int r, int tt) {
        bfrag v;
        if (!setB) {
            const float* xs = inputs + ((size_t)(b0 + lm) * Tt + tt) * 512 + r * 32 + q * 8;
            float4 a = *(const float4*)xs, b = *(const float4*)(xs + 4);
            v[0]=(short)f2bf(a.x); v[1]=(short)f2bf(a.y); v[2]=(short)f2bf(a.z); v[3]=(short)f2bf(a.w);
            v[4]=(short)f2bf(b.x); v[5]=(short)f2bf(b.y); v[6]=(short)f2bf(b.z); v[7]=(short)f2bf(b.w);
        } else {
            const ushort* hs = ring0 + (size_t)(tt & (D0 - 1)) * (Bsz * Hsz)
                             + (b0 + lm) * 512 + r * 32 + q * 8;
            u64 q0 = __hip_atomic_load((const u64*)hs, __ATOMIC_RELAXED, __HIP_MEMORY_SCOPE_AGENT);
            u64 q1 = __hip_atomic_load((const u64*)(hs + 4), __ATOMIC_RELAXED, __HIP_MEMORY_SCOPE_AGENT);
            v = pack2(q0, q1);
        }
        *(bfrag*)&frag_lds[r * 512 + lane * 8] = v;
    };

    // ---- prologue: pre-stage non-recurrent half for t=0 (all 8 waves) ----
    if (setB) spin_agent(prog_up, 1);       // uniform addr: one request per wave
    stage_row(wave * 2, 0);
    stage_row(wave * 2 + 1, 0);

    for (int t = 0; t < Tt; ++t) {
        const int rsp = (t - 1) & (DP - 1), rsc = t & (DP - 1);

        // ---- group barrier: every wave polls the single counter line ----
        if (t > 0) {
            spin_cnt(cnt, 32 * t, fast);
            if (myidx == 0 && tid == 0)     // lagged publish: h0 up to t-2 visible
                __hip_atomic_store(prog_self, t - 1, __ATOMIC_RELAXED, __HIP_MEMORY_SCOPE_AGENT);
        }
        // ---- recurrent staging rows 16..31 from own ring (all 8 waves) ----
        {
            const ushort* hb_ = ring_own + (size_t)rsp * (Bsz * Hsz) + (b0 + lm) * 512 + q * 8;
            const ushort* p0 = hb_ + wave * 32;          // kk = wave
            const ushort* p1 = hb_ + (wave + 8) * 32;    // kk = wave+8
            bfrag v0, v1;
            if (fast) {
                i4 w0, w1;
                asm volatile(
                    "global_load_dwordx4 %0, %2, off sc0\n\t"
                    "global_load_dwordx4 %1, %3, off sc0\n\t"
                    "s_waitcnt vmcnt(0)"
                    : "=&v"(w0), "=&v"(w1) : "v"(p0), "v"(p1) : "memory");
                v0 = __builtin_bit_cast(bfrag, w0);
                v1 = __builtin_bit_cast(bfrag, w1);
            } else {
                u64 a0 = __hip_atomic_load((const u64*)p0, __ATOMIC_RELAXED, __HIP_MEMORY_SCOPE_AGENT);
                u64 a1 = __hip_atomic_load((const u64*)(p0 + 4), __ATOMIC_RELAXED, __HIP_MEMORY_SCOPE_AGENT);
                u64 c0 = __hip_atomic_load((const u64*)p1, __ATOMIC_RELAXED, __HIP_MEMORY_SCOPE_AGENT);
                u64 c1 = __hip_atomic_load((const u64*)(p1 + 4), __ATOMIC_RELAXED, __HIP_MEMORY_SCOPE_AGENT);
                v0 = pack2(a0, a1); v1 = pack2(c0, c1);
            }
            *(bfrag*)&frag_lds[(16 + wave) * 512 + lane * 8] = v0;
            *(bfrag*)&frag_lds[(24 + wave) * 512 + lane * 8] = v1;
        }
        __syncthreads();                                  // S1: frag ready

        // ---- MFMA: 16 ksteps over this wave's K-half, 2 chains ----
        cfrag C0 = {0.f, 0.f, 0.f, 0.f}, C1 = {0.f, 0.f, 0.f, 0.f};
        #pragma unroll
        for (int j = 0; j < 16; j += 2) {
            bfrag Bf0 = *(const bfrag*)&frag_lds[(g * 16 + j) * 512 + lane * 8];
            C0 = __builtin_amdgcn_mfma_f32_16x16x32_bf16(wv[j], Bf0, C0, 0, 0, 0);
            bfrag Bf1 = *(const bfrag*)&frag_lds[(g * 16 + j + 1) * 512 + lane * 8];
            C1 = __builtin_amdgcn_mfma_f32_16x16x32_bf16(wv[j + 1], Bf1, C1, 0, 0, 0);
        }
        #pragma unroll
        for (int reg = 0; reg < 4; ++reg) {
            const int lrow = tau * 16 + q * 4 + reg;      // C row (m89 layout)
            part_lds[(lrow * 17 + lm) * 2 + g] = C0[reg] + C1[reg];
        }
        __syncthreads();                                  // S2: partials ready

        if (wave == 0) {
            // ---- cell update: 4 cells/lane (mi = q*4+k, batch = lm) ----
            float hn4[4], cn4[4];
            #pragma unroll
            for (int k = 0; k < 4; ++k) {
                const int mi = q * 4 + k;
                float gs[4];
                #pragma unroll
                for (int tg = 0; tg < 4; ++tg) {
                    float2 p = *(const float2*)&part_lds[((tg * 16 + mi) * 17 + lm) * 2];
                    gs[tg] = p.x + p.y + biasw[tg][k];
                }
                float cn = sigm(gs[1]) * cc[k] + sigm(gs[0]) * ftanh(gs[3]) + slotw[k];
                float hn = sigm(gs[2]) * ftanh(cn);
                cc[k] = cn; cn4[k] = cn; hn4[k] = hn;
            }
            u64 hq = (u64)f2bf(hn4[0]) | ((u64)f2bf(hn4[1]) << 16)
                   | ((u64)f2bf(hn4[2]) << 32) | ((u64)f2bf(hn4[3]) << 48);
            const size_t poff = (size_t)(b0 + lm) * 512 + m0 + q * 4;
            ushort* rp = ring_own + (size_t)rsc * (Bsz * Hsz) + poff;
            if (fast) *(u64*)rp = hq;
            else __hip_atomic_store((u64*)rp, hq, __ATOMIC_RELAXED, __HIP_MEMORY_SCOPE_AGENT);
            // ring0 slot t&7 reuse guard (rarely binding: B trails ~3 steps)
            if (!setB && t >= D0 && lane == 0) spin_agent(prog_down, t - D0 + 1);
            asm volatile("s_waitcnt vmcnt(0)" ::: "memory");   // own-ring stores at L2
            if (lane == 0) cnt_add(cnt, fast);
            // A->B handoff AFTER the add: covered by NEXT step's vmcnt (lagged publish)
            if (!setB)
                __hip_atomic_store((u64*)(ring0 + (size_t)(t & (D0 - 1)) * (Bsz * Hsz) + poff),
                                   hq, __ATOMIC_RELAXED, __HIP_MEMORY_SCOPE_AGENT);
            // deferred output stores (off the pacing path)
            if (setB) {
                float4 o = {hn4[0], hn4[1], hn4[2], hn4[3]};
                *(float4*)(out + ((size_t)(b0 + lm) * Tt + t) * Hsz + m0 + q * 4) = o;
            }
            if (t == Tt - 1) {
                float4 oh = {hn4[0], hn4[1], hn4[2], hn4[3]};
                float4 oc = {cn4[0], cn4[1], cn4[2], cn4[3]};
                *(float4*)(out + OUT_HT + (size_t)(b0 + lm) * 1024 + L * 512 + m0 + q * 4) = oh;
                *(float4*)(out + OUT_CT + (size_t)(b0 + lm) * 1024 + L * 512 + m0 + q * 4) = oc;
            }
        } else if (t + 1 < Tt) {
            // ---- waves 1-7: stage non-recurrent half for t+1 (overlaps wave0 tail) ----
            if (setB) spin_agent(prog_up, t + 2);          // uniform addr per wave
            for (int r = wave - 1; r < 16; r += 7) stage_row(r, t + 1);
        }
    }
    // ---- epilogue (A): drain last ring0 stores, extra add, final publish ----
    if (!setB && wave == 0) {
        asm volatile("s_waitcnt vmcnt(0)" ::: "memory");
        if (lane == 0) cnt_add(cnt, fast);
        if (myidx == 0 && lane == 0) {
            spin_cnt(cnt, 32 * Tt + 32, fast);
            __hip_atomic_store(prog_self, Tt, __ATOMIC_RELAXED, __HIP_MEMORY_SCOPE_AGENT);
        }
    }
}

extern "C" void kernel_launch(void* const* d_in, const int* in_sizes, int n_in,
                              void* d_out, int out_size, void* d_ws, size_t ws_size,
                              hipStream_t stream) {
    (void)in_sizes; (void)n_in; (void)out_size; (void)ws_size;
    const float* inputs = (const float*)d_in[0];
    const float* gW = (const float*)d_in[5];
    const float* gb = (const float*)d_in[6];
    const float* sbias = (const float*)d_in[8];
    float* out = (float*)d_out;
    float* ws = (float*)d_ws;

    hipLaunchKernelGGL(sclstm_init, dim3(256), dim3(256), 0, stream, ws, out);
    hipLaunchKernelGGL(sclstm_main, dim3(NBLK), dim3(NTHR), 0, stream,
                       inputs, gW, gb, sbias, out, ws);
}

// Round 3
// 5169.483 us; speedup vs baseline: 2.9319x; 2.9319x over previous
//
#include <hip/hip_runtime.h>

// SCLSTM on MI355X — R7: R5 sync fabric (flag array + single-wave spin) restored,
// + T14 split staging (issue post-S1, unpack in window), raw barriers with counted
// waits, ring0 stores deferred to next top (lagged certification), 16-block groups
// (one sync group per XCD, 32 features/block, 128-VGPR weight set).
//
// R6 post-mortem: single shared counter + mass polling = coherence-traffic DoS
// (8.3x regression at identical byte counts). Never centralize spin targets.
//
// Dead code (verified R1-R3): s==0 forever => st==0, slot_info==tanh(sb[l]).
// Remaining: 2-layer LSTM B=64,T=512,H=512; layers pipelined on disjoint sets.
//
// Certification protocol (lagged): A stores ring0(t-1) at TOP of body(t) (after
// the staging vmcnt so its MALL ack never stalls the chain); S4's vmcnt(0) at
// body(t) drains it; flags(t)=t+1 certify it; publisher then stores prog=t
// meaning "h0(<=t-1) readable". B stages h0(tt) only when prog_up >= tt+1.
// Backpressure: A needs prog_down >= t-8 before overwriting ring0 slot (t-1)&7
// (B publishes prog_down=t+1 at its spin-pass(t)); shadow-cached, never binds.

typedef unsigned short ushort;
typedef unsigned int uint;
typedef unsigned long long u64;
using bfrag = __attribute__((ext_vector_type(8))) short;
using cfrag = __attribute__((ext_vector_type(4))) float;
using i4    = __attribute__((ext_vector_type(4))) int;

constexpr int NBLK = 128, NTHR = 512;
constexpr int Bsz = 64, Tt = 512, Hsz = 512;
constexpr int D0 = 8;                     // ring0 (A->B) depth
constexpr int DP = 2;                     // private recurrence ring depth

constexpr long long OUT_HT = (long long)Bsz * Tt * Hsz;
constexpr long long OUT_CT = OUT_HT + (long long)Bsz * 2 * Hsz;
constexpr long long OUT_ST = OUT_CT + (long long)Bsz * 2 * Hsz;

// ws layout (bytes)
constexpr int WS_SLOTS_A = 0;                                 // 4 grp x 16 x 16 ints
constexpr int WS_SLOTS_B = 8 * 1024;
constexpr int WS_PROG_A  = 16 * 1024;
constexpr int WS_PROG_B  = 17 * 1024;
constexpr int WS_XCC     = 18 * 1024;                         // 8 x 16 x 16 ints
constexpr int WS_RING0   = 64 * 1024;                         // D0 x 64 x 512 ushort
constexpr int WS_RING1   = WS_RING0 + D0 * Bsz * Hsz * 2;     // DP x ... (B private)
constexpr int WS_RINGA   = WS_RING1 + DP * Bsz * Hsz * 2;     // DP x ... (A private)
constexpr int WS_TOTAL   = WS_RINGA + DP * Bsz * Hsz * 2;

__global__ __launch_bounds__(256) void sclstm_init(float* __restrict__ ws,
                                                   float* __restrict__ out) {
    int i = blockIdx.x * blockDim.x + threadIdx.x, st = gridDim.x * blockDim.x;
    for (int k = i; k < WS_TOTAL / 4; k += st) ws[k] = 0.f;
    for (int k = i; k < Bsz * 128; k += st) out[OUT_ST + k] = 0.f;  // st == 0 always
}

__device__ __forceinline__ float sigm(float x) { return 1.f / (1.f + __expf(-x)); }
__device__ __forceinline__ float ftanh(float x) {
    float e = __expf(2.f * x);
    return 1.f - 2.f / (e + 1.f);
}
__device__ __forceinline__ ushort f2bf(float f) {
    unsigned u = __builtin_bit_cast(unsigned, f);
    u += 0x7FFFu + ((u >> 16) & 1u);
    return (ushort)(u >> 16);
}
__device__ __forceinline__ int aload(const int* p) {
    return __hip_atomic_load(p, __ATOMIC_RELAXED, __HIP_MEMORY_SCOPE_AGENT);
}
__device__ __forceinline__ int load_sc0(const int* p) {   // bypass L1, read own-XCD L2
    int v;
    asm volatile("global_load_dword %0, %1, off sc0\n\ts_waitcnt vmcnt(0)"
                 : "=v"(v) : "v"(p) : "memory");
    return v;
}
__device__ __forceinline__ void spin_agent(const int* p, int v) {
    int it = 0;
    while (aload(p) < v) {
        __builtin_amdgcn_s_sleep(1);
        if (((++it) & 1023) == 0)
            __builtin_amdgcn_fence(__ATOMIC_ACQUIRE, "agent");  // safety net only
    }
}
__device__ __forceinline__ void spin_f(const int* p, int v, int fast) {
    if (fast) {
        int it = 0;
        while (load_sc0(p) < v) {
            __builtin_amdgcn_s_sleep(1);
            if (((++it) & 63) == 0)
                __builtin_amdgcn_fence(__ATOMIC_ACQUIRE, "agent");  // safety net only
        }
    } else {
        spin_agent(p, v);
    }
}
__device__ __forceinline__ void st_flag(int* p, int v, int fast) {
    if (fast) __hip_atomic_store(p, v, __ATOMIC_RELAXED, __HIP_MEMORY_SCOPE_WORKGROUP);
    else      __hip_atomic_store(p, v, __ATOMIC_RELAXED, __HIP_MEMORY_SCOPE_AGENT);
}
__device__ __forceinline__ bfrag pack2(u64 q0, u64 q1) {
    bfrag v;
    v[0]=(short)(ushort)(q0); v[1]=(short)(ushort)(q0 >> 16);
    v[2]=(short)(ushort)(q0 >> 32); v[3]=(short)(ushort)(q0 >> 48);
    v[4]=(short)(ushort)(q1); v[5]=(short)(ushort)(q1 >> 16);
    v[6]=(short)(ushort)(q1 >> 32); v[7]=(short)(ushort)(q1 >> 48);
    return v;
}
__device__ __forceinline__ bfrag packf(float4 a, float4 b) {
    bfrag v;
    v[0]=(short)f2bf(a.x); v[1]=(short)f2bf(a.y); v[2]=(short)f2bf(a.z); v[3]=(short)f2bf(a.w);
    v[4]=(short)f2bf(b.x); v[5]=(short)f2bf(b.y); v[6]=(short)f2bf(b.z); v[7]=(short)f2bf(b.w);
    return v;
}
// raw barriers with counted waits (rule 18: sched_barrier after the waitcnt)
__device__ __forceinline__ void bar_lgkm() {
    asm volatile("s_waitcnt lgkmcnt(0)" ::: "memory");
    __builtin_amdgcn_sched_barrier(0);
    __builtin_amdgcn_s_barrier();
}
__device__ __forceinline__ void bar_vm0() {
    asm volatile("s_waitcnt vmcnt(0) lgkmcnt(0)" ::: "memory");
    __builtin_amdgcn_sched_barrier(0);
    __builtin_amdgcn_s_barrier();
}
__device__ __forceinline__ void bar_raw() {
    __builtin_amdgcn_s_barrier();
}

__global__ __launch_bounds__(NTHR, 2) void sclstm_main(
    const float* __restrict__ inputs,   // (B,T,512) fp32
    const float* __restrict__ gW,       // (2, 2048, 1024) fp32
    const float* __restrict__ gb,       // (2, 2048)
    const float* __restrict__ sbias,    // (2, 512)
    float* __restrict__ out,
    float* __restrict__ ws)
{
    __shared__ __attribute__((aligned(16))) ushort frag_lds[32 * 512]; // 32 ks x 1KB
    __shared__ float part_lds[128 * 17 * 2];  // [(lrow*17 + col)*2 + g]
    __shared__ int fast_sh;

    char* wsb = (char*)ws;
    const int tid = threadIdx.x, blk = blockIdx.x;
    const int group = blk & 7;                 // intended XCD under round-robin
    const int setB = group & 1;                // 0: layer0 (producer), 1: layer1
    const int grp  = group >> 1;               // batch tile
    const int myidx = blk >> 3;                // 0..15 feature tile within group
    const int L = setB;
    const int b0 = grp * 16, m0 = myidx * 32;

    int* slots     = (int*)(wsb + (setB ? WS_SLOTS_B : WS_SLOTS_A)) + grp * 16 * 16;
    int* prog_self = (int*)(wsb + (setB ? WS_PROG_B : WS_PROG_A)) + grp * 16;
    int* prog_up   = (int*)(wsb + WS_PROG_A) + grp * 16;   // B waits: h0 certified
    int* prog_down = (int*)(wsb + WS_PROG_B) + grp * 16;   // A ring0 backpressure
    ushort* ring0 = (ushort*)(wsb + WS_RING0);
    ushort* ring1 = (ushort*)(wsb + WS_RING1);
    ushort* ringA = (ushort*)(wsb + WS_RINGA);
    ushort* ring_own = setB ? ring1 : ringA;   // private recurrence ring (L2-local)

    const int lane = tid & 63, wave = tid >> 6;
    const int tau = wave & 3, g = wave >> 2;   // gate tile, K-half (512 each)
    const int q = lane >> 4, lm = lane & 15;

    // ---- one-time: weights -> A-fragments, 2 M-subtiles x 16 ksteps = 128 VGPRs ----
    bfrag wv[2][16];
    #pragma unroll
    for (int m = 0; m < 2; ++m) {
        const int grow = tau * 512 + m0 + m * 16 + lm;
        const float* wrow = gW + ((size_t)L * 2048 + grow) * 1024 + g * 512 + q * 8;
        #pragma unroll
        for (int j = 0; j < 16; ++j) {
            const float* src = wrow + j * 32;
            wv[m][j] = packf(*(const float4*)src, *(const float4*)(src + 4));
        }
    }
    // ---- cell constants (tid<256): 2 features (2mp, 2mp+1), batch b3 ----
    const int mp = tid & 15, b3 = tid >> 4;    // b3 valid for tid<256
    float bias2[4][2], slot2[2], cc2[2] = {0.f, 0.f};
    float hnf2[2] = {0.f, 0.f};
    uint hq_hold = 0;
    if (tid < 256) {
        #pragma unroll
        for (int k = 0; k < 2; ++k) {
            #pragma unroll
            for (int tg = 0; tg < 4; ++tg)
                bias2[tg][k] = gb[L * 2048 + tg * 512 + m0 + 2 * mp + k];
            slot2[k] = ftanh(sbias[L * 512 + m0 + 2 * mp + k]);
        }
    }

    // ---- runtime check: is this sync group on one XCD? (agent fallback if not) ----
    int fast;
    {
        unsigned xcc = (unsigned)__builtin_amdgcn_s_getreg((31 << 11) | 20) & 0xFu; // HW_REG_XCC_ID
        int* xarr = (int*)(wsb + WS_XCC) + group * 16 * 16;
        if (tid == 0) {
            __hip_atomic_store(xarr + myidx * 16, (int)xcc + 1,
                               __ATOMIC_RELAXED, __HIP_MEMORY_SCOPE_AGENT);
            int ok = 1, ref = 0;
            for (int i = 0; i < 16; ++i) {
                int v;
                while ((v = aload(xarr + i * 16)) == 0) __builtin_amdgcn_s_sleep(2);
                if (i == 0) ref = v; else ok &= (v == ref);
            }
            fast_sh = ok;
        }
        __syncthreads();
        fast = fast_sh;
    }

    // ---- prologue: direct-stage non-recurrent rows 0..15 for t=0 ----
    if (setB) {
        if (tid == 0) spin_agent(prog_up, 1);   // h0(0) certified
        __syncthreads();
    }
    #pragma unroll
    for (int it = 0; it < 2; ++it) {
        const int r = wave * 2 + it;
        bfrag v;
        if (!setB) {
            const float* xs = inputs + ((size_t)(b0 + lm) * Tt + 0) * 512 + r * 32 + q * 8;
            v = packf(*(const float4*)xs, *(const float4*)(xs + 4));
        } else {
            const ushort* hs = ring0 + (b0 + lm) * 512 + r * 32 + q * 8;  // slot 0
            u64 q0 = __hip_atomic_load((const u64*)hs, __ATOMIC_RELAXED, __HIP_MEMORY_SCOPE_AGENT);
            u64 q1 = __hip_atomic_load((const u64*)(hs + 4), __ATOMIC_RELAXED, __HIP_MEMORY_SCOPE_AGENT);
            v = pack2(q0, q1);
        }
        *(bfrag*)&frag_lds[r * 512 + lane * 8] = v;
    }

    int cach_down = 0;          // A: shadow of prog_down (monotone)
    float4 pxa[3][2];           // A: x prefetch regs (3 rows x 32B)
    u64 phb[3][2];              // B: h0 prefetch regs

    for (int t = 0; t < Tt; ++t) {
        const int rsp = (t - 1) & (DP - 1), rsc = t & (DP - 1);

        // ======== TOP ========
        // recurrent staging rows 16..31 from own ring (all 8 waves) FIRST,
        // so the asm vmcnt(0) never waits on stores issued below.
        {
            const ushort* hb_ = ring_own + (size_t)rsp * (Bsz * Hsz) + (b0 + lm) * 512 + q * 8;
            const ushort* p0 = hb_ + wave * 32;
            const ushort* p1 = hb_ + (wave + 8) * 32;
            bfrag v0, v1;
            if (fast) {
                i4 w0, w1;
                asm volatile(
                    "global_load_dwordx4 %0, %2, off sc0\n\t"
                    "global_load_dwordx4 %1, %3, off sc0\n\t"
                    "s_waitcnt vmcnt(0)"
                    : "=&v"(w0), "=&v"(w1) : "v"(p0), "v"(p1) : "memory");
                v0 = __builtin_bit_cast(bfrag, w0);
                v1 = __builtin_bit_cast(bfrag, w1);
            } else {
                u64 a0 = __hip_atomic_load((const u64*)p0, __ATOMIC_RELAXED, __HIP_MEMORY_SCOPE_AGENT);
                u64 a1 = __hip_atomic_load((const u64*)(p0 + 4), __ATOMIC_RELAXED, __HIP_MEMORY_SCOPE_AGENT);
                u64 c0 = __hip_atomic_load((const u64*)p1, __ATOMIC_RELAXED, __HIP_MEMORY_SCOPE_AGENT);
                u64 c1 = __hip_atomic_load((const u64*)(p1 + 4), __ATOMIC_RELAXED, __HIP_MEMORY_SCOPE_AGENT);
                v0 = pack2(a0, a1); v1 = pack2(c0, c1);
            }
            *(bfrag*)&frag_lds[(16 + wave) * 512 + lane * 8] = v0;
            *(bfrag*)&frag_lds[(24 + wave) * 512 + lane * 8] = v1;
        }
        // deferred stores (acks drain free at S4): A ring0(t-1), B out(t-1)
        int pv_now = 0x7fffffff;
        if (t > 0 && tid < 256) {
            if (!setB) {
                const int tgt = t - 8;                    // B passed body(t-8)
                if (tgt > 0 && cach_down < tgt) {
                    do { __builtin_amdgcn_s_sleep(1); cach_down = aload(prog_down); }
                    while (cach_down < tgt);
                }
                ushort* rp = ring0 + (size_t)((t - 1) & (D0 - 1)) * (Bsz * Hsz)
                           + (b0 + b3) * 512 + m0 + 2 * mp;
                __hip_atomic_store((uint*)rp, hq_hold, __ATOMIC_RELAXED, __HIP_MEMORY_SCOPE_AGENT);
            } else {
                float2 o = {hnf2[0], hnf2[1]};
                *(float2*)(out + ((size_t)(b0 + b3) * Tt + (t - 1)) * Hsz + m0 + 2 * mp) = o;
            }
        }
        if (setB && wave > 0 && t + 1 < Tt)
            pv_now = aload(prog_up);                      // non-blocking poll, used post-S1

        bar_lgkm();                                       // S1: frag ready (LDS only)

        // ======== post-S1: prefetch issue (waves 1..7) ========
        if (wave > 0 && t + 1 < Tt) {
            if (setB && pv_now < t + 2) spin_agent(prog_up, t + 2);
            #pragma unroll
            for (int it = 0; it < 3; ++it) {
                const int r = wave - 1 + it * 7;
                if (r < 16) {
                    if (!setB) {
                        const float* xs = inputs + ((size_t)(b0 + lm) * Tt + (t + 1)) * 512 + r * 32 + q * 8;
                        pxa[it][0] = *(const float4*)xs;
                        pxa[it][1] = *(const float4*)(xs + 4);
                    } else {
                        const ushort* hs = ring0 + (size_t)((t + 1) & (D0 - 1)) * (Bsz * Hsz)
                                         + (b0 + lm) * 512 + r * 32 + q * 8;
                        phb[it][0] = __hip_atomic_load((const u64*)hs, __ATOMIC_RELAXED, __HIP_MEMORY_SCOPE_AGENT);
                        phb[it][1] = __hip_atomic_load((const u64*)(hs + 4), __ATOMIC_RELAXED, __HIP_MEMORY_SCOPE_AGENT);
                    }
                }
            }
            asm volatile("" ::: "memory");                // pin issue point
        }

        // ======== MFMA: 2 M-subtiles x 16 ksteps, 4 chains ========
        cfrag C00 = {0,0,0,0}, C01 = {0,0,0,0}, C10 = {0,0,0,0}, C11 = {0,0,0,0};
        #pragma unroll
        for (int j = 0; j < 16; j += 2) {
            bfrag Bf0 = *(const bfrag*)&frag_lds[(g * 16 + j) * 512 + lane * 8];
            bfrag Bf1 = *(const bfrag*)&frag_lds[(g * 16 + j + 1) * 512 + lane * 8];
            C00 = __builtin_amdgcn_mfma_f32_16x16x32_bf16(wv[0][j],     Bf0, C00, 0, 0, 0);
            C10 = __builtin_amdgcn_mfma_f32_16x16x32_bf16(wv[1][j],     Bf0, C10, 0, 0, 0);
            C01 = __builtin_amdgcn_mfma_f32_16x16x32_bf16(wv[0][j + 1], Bf1, C01, 0, 0, 0);
            C11 = __builtin_amdgcn_mfma_f32_16x16x32_bf16(wv[1][j + 1], Bf1, C11, 0, 0, 0);
        }
        #pragma unroll
        for (int reg = 0; reg < 4; ++reg) {
            const int r0 = tau * 32 + q * 4 + reg;        // m=0 rows
            part_lds[(r0 * 17 + lm) * 2 + g] = C00[reg] + C01[reg];
            part_lds[((r0 + 16) * 17 + lm) * 2 + g] = C10[reg] + C11[reg];
        }
        bar_lgkm();                                       // S2: partials ready (LDS only)

        // ======== cell update (waves 0..3): 2 features x 1 batch each ========
        if (tid < 256) {
            #pragma unroll
            for (int k = 0; k < 2; ++k) {
                const int fi = 2 * mp + k;
                float gs[4];
                #pragma unroll
                for (int tg = 0; tg < 4; ++tg) {
                    float2 p = *(const float2*)&part_lds[((tg * 32 + fi) * 17 + b3) * 2];
                    gs[tg] = p.x + p.y + bias2[tg][k];
                }
                float cn = sigm(gs[1]) * cc2[k] + sigm(gs[0]) * ftanh(gs[3]) + slot2[k];
                float hn = sigm(gs[2]) * ftanh(cn);
                cc2[k] = cn; hnf2[k] = hn;
            }
            hq_hold = (uint)f2bf(hnf2[0]) | ((uint)f2bf(hnf2[1]) << 16);
            ushort* rp = ring_own + (size_t)rsc * (Bsz * Hsz) + (b0 + b3) * 512 + m0 + 2 * mp;
            if (fast) *(uint*)rp = hq_hold;
            else __hip_atomic_store((uint*)rp, hq_hold, __ATOMIC_RELAXED, __HIP_MEMORY_SCOPE_AGENT);
        }
        bar_vm0();                                        // S4: ring stores certified
        if (tid == 0) st_flag(&slots[myidx * 16], t + 1, fast);

        // ======== window: unpack prefetch (waves 1..7) || barrier detect (wave0) ====
        if (wave > 0) {
            if (t + 1 < Tt) {
                #pragma unroll
                for (int it = 0; it < 3; ++it) {
                    const int r = wave - 1 + it * 7;
                    if (r < 16) {
                        bfrag v = setB ? pack2(phb[it][0], phb[it][1])
                                       : packf(pxa[it][0], pxa[it][1]);
                        *(bfrag*)&frag_lds[r * 512 + lane * 8] = v;
                    }
                }
            }
        } else {
            if (lane < 16) spin_f(&slots[lane * 16], t + 1, fast);
            if (myidx == 0 && lane == 0)
                __hip_atomic_store(prog_self, setB ? t + 1 : t,
                                   __ATOMIC_RELAXED, __HIP_MEMORY_SCOPE_AGENT);
        }
        bar_raw();                                        // S5: rendezvous only
    }

    // ======== epilogue ========
    if (!setB) {
        // flush ring0(Tt-1), certify with one extra flag round, publish prog=Tt
        if (tid < 256) {
            const int tgt = Tt - 8;
            if (cach_down < tgt) {
                do { __builtin_amdgcn_s_sleep(1); cach_down = aload(prog_down); }
                while (cach_down < tgt);
            }
            ushort* rp = ring0 + (size_t)((Tt - 1) & (D0 - 1)) * (Bsz * Hsz)
                       + (b0 + b3) * 512 + m0 + 2 * mp;
            __hip_atomic_store((uint*)rp, hq_hold, __ATOMIC_RELAXED, __HIP_MEMORY_SCOPE_AGENT);
        }
        bar_vm0();
        if (tid == 0) st_flag(&slots[myidx * 16], Tt + 1, fast);
        if (wave == 0 && lane < 16) spin_f(&slots[lane * 16], Tt + 1, fast);
        if (myidx == 0 && tid == 0)
            __hip_atomic_store(prog_self, Tt, __ATOMIC_RELAXED, __HIP_MEMORY_SCOPE_AGENT);
        if (tid < 256) {
            float2 oh = {hnf2[0], hnf2[1]}, oc = {cc2[0], cc2[1]};
            *(float2*)(out + OUT_HT + (size_t)(b0 + b3) * 1024 + 0 * 512 + m0 + 2 * mp) = oh;
            *(float2*)(out + OUT_CT + (size_t)(b0 + b3) * 1024 + 0 * 512 + m0 + 2 * mp) = oc;
        }
    } else {
        if (tid < 256) {
            float2 oh = {hnf2[0], hnf2[1]}, oc = {cc2[0], cc2[1]};
            *(float2*)(out + ((size_t)(b0 + b3) * Tt + (Tt - 1)) * Hsz + m0 + 2 * mp) = oh;
            *(float2*)(out + OUT_HT + (size_t)(b0 + b3) * 1024 + 512 + m0 + 2 * mp) = oh;
            *(float2*)(out + OUT_CT + (size_t)(b0 + b3) * 1024 + 512 + m0 + 2 * mp) = oc;
        }
    }
}

extern "C" void kernel_launch(void* const* d_in, const int* in_sizes, int n_in,
                              void* d_out, int out_size, void* d_ws, size_t ws_size,
                              hipStream_t stream) {
    (void)in_sizes; (void)n_in; (void)out_size; (void)ws_size;
    const float* inputs = (const float*)d_in[0];
    const float* gW = (const float*)d_in[5];
    const float* gb = (const float*)d_in[6];
    const float* sbias = (const float*)d_in[8];
    float* out = (float*)d_out;
    float* ws = (float*)d_ws;

    hipLaunchKernelGGL(sclstm_init, dim3(256), dim3(256), 0, stream, ws, out);
    hipLaunchKernelGGL(sclstm_main, dim3(NBLK), dim3(NTHR), 0, stream,
                       inputs, gW, gb, sbias, out, ws);
}